// Round 6
// baseline (96.285 us; speedup 1.0000x reference)
//
#include <hip/hip_runtime.h>
#include <math.h>

#define EPSF 1e-6f

constexpr int B = 8, N = 2048, M = 16, S = 100;
constexpr int MAIN_BLOCKS = B * (N / 64);         // 256: pcl_to_prim, 64 points each
constexpr int PRIM_BLOCKS = B * M * 4;            // 512: prim_to_pcl, (b,m) x quarter-of-S
constexpr int TOTAL_BLOCKS = MAIN_BLOCKS + PRIM_BLOCKS;  // 768 = 3 blocks/CU exactly
constexpr int NPART = MAIN_BLOCKS * 4 + PRIM_BLOCKS;     // 1536 partials in d_ws

typedef float v2f __attribute__((ext_vector_type(2)));   // -> v_pk_fma_f32 pairs

// fast hw transcendentals (avoid __exp2f/__log2f: glibc math.h macro collision)
__device__ __forceinline__ float hw_exp2(float x) { return __builtin_amdgcn_exp2f(x); }
__device__ __forceinline__ float hw_log2(float x) { return __builtin_amdgcn_logf(x); }

__device__ __forceinline__ float fexp_d(float x, float p) {
    float sg = (x > 0.f) ? 1.f : ((x < 0.f) ? -1.f : 0.f);
    return sg * __powf(fabsf(x) + EPSF, p);
}

__device__ __forceinline__ float sgn_d(float x) {
    return (x > 0.f) ? 1.f : ((x < 0.f) ? -1.f : 0.f);
}

// quaternion (w,x,y,z) at rot[bm*4..] -> row-major 3x3
__device__ __forceinline__ void quat_R(const float* __restrict__ rot, int bm, float R[9]) {
    float w = rot[bm * 4 + 0], x = rot[bm * 4 + 1], y = rot[bm * 4 + 2], z = rot[bm * 4 + 3];
    float inv = 1.0f / (sqrtf(w * w + x * x + y * y + z * z) + EPSF);
    w *= inv; x *= inv; y *= inv; z *= inv;
    R[0] = 1.f - 2.f * (y * y + z * z); R[1] = 2.f * (x * y - w * z); R[2] = 2.f * (x * z + w * y);
    R[3] = 2.f * (x * y + w * z); R[4] = 1.f - 2.f * (x * x + z * z); R[5] = 2.f * (y * z - w * x);
    R[6] = 2.f * (x * z - w * y); R[7] = 2.f * (y * z + w * x); R[8] = 1.f - 2.f * (x * x + y * y);
}

// surface point (prim path; 25 pts/block, transcendental cost irrelevant there)
__device__ __forceinline__ float4 surf_point(
    const float* __restrict__ sizep, const float* __restrict__ seps,
    const float* __restrict__ deform, const float* __restrict__ etas,
    const float* __restrict__ omegas, int bm, int s)
{
    float e1 = seps[bm * 2 + 0], e2 = seps[bm * 2 + 1];
    float a1 = sizep[bm * 3 + 0], a2 = sizep[bm * 3 + 1], a3 = sizep[bm * 3 + 2];
    float d0 = deform[bm * 2 + 0], d1 = deform[bm * 2 + 1];
    float se_, ce_, sw_, cw_;
    __sincosf(etas[s], &se_, &ce_);
    __sincosf(omegas[s], &sw_, &cw_);
    float ce = fexp_d(ce_, e1);
    float se = fexp_d(se_, e1);
    float cw = fexp_d(cw_, e2);
    float sw = fexp_d(sw_, e2);
    float x = a1 * ce * cw;
    float y = a2 * ce * sw;
    float z = a3 * se;
    float fx = d0 * (z / a3) + 1.0f;
    float fy = d1 * (z / a3) + 1.0f;
    float4 P;
    P.x = fx * x; P.y = fy * y; P.z = z;
    P.w = P.x * P.x + P.y * P.y + P.z * P.z;
    return P;
}

// ---------------- single fused kernel, 768 blocks = 3/CU ----------------
// [0,256): pcl_to_prim; [256,768): prim_to_pcl (quarter-S each).
// Round-robin puts 1 main + 2 prim blocks on each CU: 12 waves/CU so prim
// waves hide main's LDS/global latency (round-5 lesson: kernel was ~27 us
// at 2 blocks/CU, latency-bound at 35% VALUBusy / 15% occupancy).
// Reducer is folded into the LAST prim block (no extra block, no imbalance).
// No same-address atomics (round-1 lesson: ~14 ns each, serialized burst).
__global__ __launch_bounds__(256) void k_all(
    const float* __restrict__ pcl, const float* __restrict__ trans,
    const float* __restrict__ rot, const float* __restrict__ sizep,
    const float* __restrict__ seps, const float* __restrict__ deform,
    const float* __restrict__ probs,
    const float* __restrict__ etas, const float* __restrict__ omegas,
    float* __restrict__ part, unsigned int* __restrict__ flags,
    float* __restrict__ out)
{
    __shared__ float4 pts[S * M];   // 25.6 KB  (prim path reuses [0..24])
    __shared__ float trig[S * 8];   // 3.2 KB: per-s {log2|c|,sgn} x {ce,se,cw,sw}
    __shared__ float sbuf[20];      // prim path: sarea[0..15], wsum[16..19]

    int t = threadIdx.x;

    if (blockIdx.x < MAIN_BLOCKS) {
        // ---------- pcl_to_prim ----------
        int b  = blockIdx.x >> 5;        // 32 n-chunks per batch
        int n0 = (blockIdx.x & 31) * 64;

        // stage 1: per-s trig+log table (sincos/log depend only on s, not m)
        if (t < S) {
            float se_, ce_, sw_, cw_;
            __sincosf(etas[t], &se_, &ce_);
            __sincosf(omegas[t], &sw_, &cw_);
            trig[t * 8 + 0] = hw_log2(fabsf(ce_) + EPSF);
            trig[t * 8 + 1] = sgn_d(ce_);
            trig[t * 8 + 2] = hw_log2(fabsf(se_) + EPSF);
            trig[t * 8 + 3] = sgn_d(se_);
            trig[t * 8 + 4] = hw_log2(fabsf(cw_) + EPSF);
            trig[t * 8 + 5] = sgn_d(cw_);
            trig[t * 8 + 6] = hw_log2(fabsf(sw_) + EPSF);
            trig[t * 8 + 7] = sgn_d(sw_);
        }
        __syncthreads();

        // stage 2: 1600 surface points, 4 exp2 each
        for (int i = t; i < S * M; i += 256) {
            int s = i >> 4, mm = i & 15;
            int bmi = b * M + mm;
            float e1 = seps[bmi * 2 + 0], e2 = seps[bmi * 2 + 1];
            float a1 = sizep[bmi * 3 + 0], a2 = sizep[bmi * 3 + 1], a3 = sizep[bmi * 3 + 2];
            float d0 = deform[bmi * 2 + 0], d1 = deform[bmi * 2 + 1];
            float ce = trig[s * 8 + 1] * hw_exp2(e1 * trig[s * 8 + 0]);
            float se = trig[s * 8 + 3] * hw_exp2(e1 * trig[s * 8 + 2]);
            float cw = trig[s * 8 + 5] * hw_exp2(e2 * trig[s * 8 + 4]);
            float sw = trig[s * 8 + 7] * hw_exp2(e2 * trig[s * 8 + 6]);
            float x = a1 * ce * cw;
            float y = a2 * ce * sw;
            float z = a3 * se;
            float fx = fmaf(d0, se, 1.0f);   // z/a3 == se
            float fy = fmaf(d1, se, 1.0f);
            float4 P;
            P.x = fx * x; P.y = fy * y; P.z = z;
            P.w = P.x * P.x + P.y * P.y + P.z * P.z;
            pts[i] = P;
        }
        __syncthreads();

        int m  = t & 15;
        int nl = t >> 4;
        int bm = b * M + m;
        float R[9];
        quat_R(rot, bm, R);
        float tx = trans[bm * 3 + 0], ty = trans[bm * 3 + 1], tz = trans[bm * 3 + 2];

        // rotated points; j packed in pairs for v_pk_fma_f32
        v2f mx2[2], my2[2], mz2[2], dmin2[2];
        float psq[4];
#pragma unroll
        for (int j = 0; j < 4; j++) {
            int n = n0 + nl + 16 * j;
            float px = pcl[(b * N + n) * 3 + 0];
            float py = pcl[(b * N + n) * 3 + 1];
            float pz = pcl[(b * N + n) * 3 + 2];
            float dx = px - tx, dy = py - ty, dz = pz - tz;
            float X = R[0] * dx + R[1] * dy + R[2] * dz;
            float Y = R[3] * dx + R[4] * dy + R[5] * dz;
            float Z = R[6] * dx + R[7] * dy + R[8] * dz;
            mx2[j >> 1][j & 1] = -2.f * X;
            my2[j >> 1][j & 1] = -2.f * Y;
            mz2[j >> 1][j & 1] = -2.f * Z;
            psq[j] = X * X + Y * Y + Z * Z;
            dmin2[j >> 1][j & 1] = 3.4e38f;
        }

        // min over s of (|P|^2 - 2 P.pt); ping-pong buffers, manual 2x unroll
        auto compute4 = [&](const float4* P4) {
#pragma unroll
            for (int u = 0; u < 4; u++) {
                float4 P = P4[u];
                v2f vx = {P.x, P.x}, vy = {P.y, P.y}, vz = {P.z, P.z}, vw = {P.w, P.w};
#pragma unroll
                for (int p = 0; p < 2; p++) {
                    v2f d = __builtin_elementwise_fma(vx, mx2[p], vw);
                    d = __builtin_elementwise_fma(vy, my2[p], d);
                    d = __builtin_elementwise_fma(vz, mz2[p], d);
                    dmin2[p] = __builtin_elementwise_min(dmin2[p], d);
                }
            }
        };

        float4 Pa[4], Pb[4];
#pragma unroll
        for (int u = 0; u < 4; u++) Pa[u] = pts[u * M + m];
        for (int g = 0; g < 24; g += 2) {           // groups of 4 s; 25 groups total
#pragma unroll
            for (int u = 0; u < 4; u++) Pb[u] = pts[(4 * (g + 1) + u) * M + m];
            compute4(Pa);
#pragma unroll
            for (int u = 0; u < 4; u++) Pa[u] = pts[(4 * (g + 2) + u) * M + m];
            compute4(Pb);
        }
        compute4(Pa);                               // group 24 (s=96..99)

        // ---- in-wave cumprod-sorted sum ----
        float ompr[16];
#pragma unroll
        for (int k = 0; k < 16; k++) ompr[k] = 1.f - probs[b * M + k];
        float pv  = probs[bm];
        float acc = 0.f;
#pragma unroll
        for (int j = 0; j < 4; j++) {
            float key = dmin2[j >> 1][j & 1] + psq[j];
            float prod = 1.f;
#pragma unroll
            for (int k = 0; k < 16; k++) {
                float bk = __shfl(key, k, 16);
                bool before = (bk < key) || (bk == key && k < m);
                prod *= before ? ompr[k] : 1.f;
            }
            acc += key * pv * prod;
        }
        for (int off = 32; off >= 1; off >>= 1) acc += __shfl_down(acc, off);
        if ((t & 63) == 0)
            __hip_atomic_store(&part[blockIdx.x * 4 + (t >> 6)],
                               acc * (1.0f / (B * N)),
                               __ATOMIC_RELAXED, __HIP_MEMORY_SCOPE_AGENT);
        __syncthreads();   // all four partial stores issued before flag
        if (t == 0)
            __hip_atomic_store(&flags[blockIdx.x], 1u,
                               __ATOMIC_RELEASE, __HIP_MEMORY_SCOPE_AGENT);
    } else {
        // ---------- prim_to_pcl (quarter-S per block) ----------
        int pb = blockIdx.x - MAIN_BLOCKS;   // [0,512)
        int bm = pb >> 2, q = pb & 3;
        int b = bm >> 4, m = bm & 15;
        int s0 = q * 25;

        float4* spts = pts;          // [0..24]  (local s indices)
        float* sarea = sbuf;         // [0..15]
        float* wsum  = sbuf + 16;    // [16..19]

        if (t < 25) spts[t] = surf_point(sizep, seps, deform, etas, omegas, bm, s0 + t);
        if (t >= 64 && t < 64 + M) {
            int mm = t - 64;
            float s0s = sizep[(b * M + mm) * 3 + 0];
            float s1s = sizep[(b * M + mm) * 3 + 1];
            float s2s = sizep[(b * M + mm) * 3 + 2];
            float tt = __powf(s0s * s1s, 1.6f) / 3.f + __powf(s0s * s2s, 1.6f) / 3.f
                     + __powf(s1s * s2s, 1.6f) / 3.f;
            sarea[mm] = 4.0f * 3.14159265358979323846f * __powf(tt, 0.625f);
        }
        __syncthreads();

        float R[9];
        quat_R(rot, bm, R);
        float tx = trans[bm * 3 + 0], ty = trans[bm * 3 + 1], tz = trans[bm * 3 + 2];

        int w = t >> 6, lane = t & 63;
        int cnt  = (w == 0) ? 7 : 6;                 // 7+6+6+6 = 25 s per block
        int offl = (w == 0) ? 0 : (7 + (w - 1) * 6); // local slot base

        // 8 slots packed into 4 v2f pairs (pads map to slot offl, masked later)
        v2f px2[4], py2[4], pz2[4], mins2[4];
#pragma unroll
        for (int k = 0; k < 8; k++) {
            int sl = (k < cnt) ? (offl + k) : offl;
            float4 P = spts[sl];
            px2[k >> 1][k & 1] = P.x;
            py2[k >> 1][k & 1] = P.y;
            pz2[k >> 1][k & 1] = P.z;
            mins2[k >> 1][k & 1] = 3.4e38f;
        }

        // min over n; 1-deep global prefetch hides L2 latency; packed fma body
        const float* pcb = pcl + b * N * 3;
        float cx = pcb[lane * 3 + 0], cy = pcb[lane * 3 + 1], cz = pcb[lane * 3 + 2];
        for (int i = 0; i < 32; i++) {
            int n2 = (i < 31) ? ((i + 1) * 64 + lane) : lane;
            float nx = pcb[n2 * 3 + 0], ny = pcb[n2 * 3 + 1], nz = pcb[n2 * 3 + 2];
            float dx = cx - tx, dy = cy - ty, dz = cz - tz;
            float X = R[0] * dx + R[1] * dy + R[2] * dz;
            float Y = R[3] * dx + R[4] * dy + R[5] * dz;
            float Z = R[6] * dx + R[7] * dy + R[8] * dz;
            float Xsq = X * X + Y * Y + Z * Z;
            v2f vmX = {-2.f * X, -2.f * X}, vmY = {-2.f * Y, -2.f * Y};
            v2f vmZ = {-2.f * Z, -2.f * Z}, vXq = {Xsq, Xsq};
#pragma unroll
            for (int k = 0; k < 4; k++) {
                v2f d = __builtin_elementwise_fma(px2[k], vmX, vXq);
                d = __builtin_elementwise_fma(py2[k], vmY, d);
                d = __builtin_elementwise_fma(pz2[k], vmZ, d);
                mins2[k] = __builtin_elementwise_min(mins2[k], d);
            }
            cx = nx; cy = ny; cz = nz;
        }

        float sum = 0.f;
#pragma unroll
        for (int k = 0; k < 8; k++) {
            float v = mins2[k >> 1][k & 1];
            for (int o = 32; o >= 1; o >>= 1) v = fminf(v, __shfl_down(v, o));
            int sl = (k < cnt) ? (offl + k) : offl;
            v += spts[sl].w;
            sum += (k < cnt) ? v : 0.f;
        }

        if (lane == 0) wsum[w] = sum;
        __syncthreads();
        if (t == 0) {
            float total = wsum[0] + wsum[1] + wsum[2] + wsum[3];
            float asum = 0.f;
            for (int mm = 0; mm < M; mm++) asum += sarea[mm];
            float area = (float)M * sarea[m] / asum;
            __hip_atomic_store(&part[MAIN_BLOCKS * 4 + pb],
                               total * area * (1.0f / (S * B * M)),
                               __ATOMIC_RELAXED, __HIP_MEMORY_SCOPE_AGENT);
            __hip_atomic_store(&flags[blockIdx.x], 1u,
                               __ATOMIC_RELEASE, __HIP_MEMORY_SCOPE_AGENT);
        }

        // ---------- reducer folded into the last prim block ----------
        // Waits on workers (never the other way). Safe without co-residency:
        // it only reads flags that workers will eventually set.
        if (blockIdx.x == TOTAL_BLOCKS - 1 && t < 64) {
            for (int i = t; i < TOTAL_BLOCKS; i += 64) {
                while (__hip_atomic_load(&flags[i], __ATOMIC_ACQUIRE,
                                         __HIP_MEMORY_SCOPE_AGENT) != 1u)
                    __builtin_amdgcn_s_sleep(2);
            }
            __threadfence();
            float ssum = 0.f;
            for (int i = t; i < NPART; i += 64)
                ssum += __hip_atomic_load(&part[i], __ATOMIC_RELAXED,
                                          __HIP_MEMORY_SCOPE_AGENT);
            for (int off = 32; off >= 1; off >>= 1) ssum += __shfl_down(ssum, off);
            if (t == 0) out[0] = ssum;
            // self-reset so replay is correct even if ws poisoning is skipped
            for (int i = t; i < TOTAL_BLOCKS; i += 64)
                __hip_atomic_store(&flags[i], 0u, __ATOMIC_RELAXED,
                                   __HIP_MEMORY_SCOPE_AGENT);
        }
    }
}

extern "C" void kernel_launch(void* const* d_in, const int* in_sizes, int n_in,
                              void* d_out, int out_size, void* d_ws, size_t ws_size,
                              hipStream_t stream)
{
    const float* pcl    = (const float*)d_in[0];
    const float* trans  = (const float*)d_in[1];
    const float* rot    = (const float*)d_in[2];
    const float* sizep  = (const float*)d_in[3];
    const float* seps   = (const float*)d_in[4];
    const float* deform = (const float*)d_in[5];
    const float* probs  = (const float*)d_in[6];
    const float* etas   = (const float*)d_in[7];
    const float* omegas = (const float*)d_in[8];
    float* out = (float*)d_out;
    float* partials = (float*)d_ws;                       // [0, 6144) bytes
    unsigned int* flags = (unsigned int*)((char*)d_ws + 8192);  // [8192, 11264)

    k_all<<<TOTAL_BLOCKS, 256, 0, stream>>>(pcl, trans, rot, sizep, seps,
                                            deform, probs, etas, omegas,
                                            partials, flags, out);
}

// Round 8
// 91.850 us; speedup vs baseline: 1.0483x; 1.0483x over previous
//
#include <hip/hip_runtime.h>
#include <math.h>

#define EPSF 1e-6f

constexpr int B = 8, N = 2048, M = 16, S = 100;
constexpr int MAIN_BLOCKS = B * (N / 64);         // 256: pcl_to_prim, 64 points each
constexpr int PRIM_BLOCKS = B * M * 2;            // 256: prim_to_pcl, (b,m) x half-of-S
constexpr int TOTAL_BLOCKS = MAIN_BLOCKS + PRIM_BLOCKS;  // 512 worker blocks
constexpr int NPART = MAIN_BLOCKS * 4 + PRIM_BLOCKS;     // 1280 partials in d_ws

typedef float v2f __attribute__((ext_vector_type(2)));   // -> v_pk_fma_f32 pairs

// fast hw transcendentals (avoid __exp2f/__log2f: glibc math.h macro collision)
__device__ __forceinline__ float hw_exp2(float x) { return __builtin_amdgcn_exp2f(x); }
__device__ __forceinline__ float hw_log2(float x) { return __builtin_amdgcn_logf(x); }

__device__ __forceinline__ float fexp_d(float x, float p) {
    float sg = (x > 0.f) ? 1.f : ((x < 0.f) ? -1.f : 0.f);
    return sg * __powf(fabsf(x) + EPSF, p);
}

__device__ __forceinline__ float sgn_d(float x) {
    return (x > 0.f) ? 1.f : ((x < 0.f) ? -1.f : 0.f);
}

// quaternion (w,x,y,z) at rot[bm*4..] -> row-major 3x3
__device__ __forceinline__ void quat_R(const float* __restrict__ rot, int bm, float R[9]) {
    float w = rot[bm * 4 + 0], x = rot[bm * 4 + 1], y = rot[bm * 4 + 2], z = rot[bm * 4 + 3];
    float inv = 1.0f / (sqrtf(w * w + x * x + y * y + z * z) + EPSF);
    w *= inv; x *= inv; y *= inv; z *= inv;
    R[0] = 1.f - 2.f * (y * y + z * z); R[1] = 2.f * (x * y - w * z); R[2] = 2.f * (x * z + w * y);
    R[3] = 2.f * (x * y + w * z); R[4] = 1.f - 2.f * (x * x + z * z); R[5] = 2.f * (y * z - w * x);
    R[6] = 2.f * (x * z - w * y); R[7] = 2.f * (y * z + w * x); R[8] = 1.f - 2.f * (x * x + y * y);
}

// surface point (prim path; 50 pts/block, transcendental cost irrelevant there)
__device__ __forceinline__ float4 surf_point(
    const float* __restrict__ sizep, const float* __restrict__ seps,
    const float* __restrict__ deform, const float* __restrict__ etas,
    const float* __restrict__ omegas, int bm, int s)
{
    float e1 = seps[bm * 2 + 0], e2 = seps[bm * 2 + 1];
    float a1 = sizep[bm * 3 + 0], a2 = sizep[bm * 3 + 1], a3 = sizep[bm * 3 + 2];
    float d0 = deform[bm * 2 + 0], d1 = deform[bm * 2 + 1];
    float se_, ce_, sw_, cw_;
    __sincosf(etas[s], &se_, &ce_);
    __sincosf(omegas[s], &sw_, &cw_);
    float ce = fexp_d(ce_, e1);
    float se = fexp_d(se_, e1);
    float cw = fexp_d(cw_, e2);
    float sw = fexp_d(sw_, e2);
    float x = a1 * ce * cw;
    float y = a2 * ce * sw;
    float z = a3 * se;
    float fx = d0 * (z / a3) + 1.0f;
    float fy = d1 * (z / a3) + 1.0f;
    float4 P;
    P.x = fx * x; P.y = fy * y; P.z = z;
    P.w = P.x * P.x + P.y * P.y + P.z * P.z;
    return P;
}

// ---------------- single fused kernel, 513 blocks ----------------
// [0,256): pcl_to_prim; [256,512): prim_to_pcl; block 512: flag-gated reducer.
// (Round-6 lesson: do NOT split prim further / grow the grid — per-CU time is
// the sum of resident waves' issued work; the 768-block split doubled prim's
// fixed per-iteration cost and regressed +6us. This is the proven-best
// structure; changes below only REMOVE issued instructions.)
__global__ __launch_bounds__(256) void k_all(
    const float* __restrict__ pcl, const float* __restrict__ trans,
    const float* __restrict__ rot, const float* __restrict__ sizep,
    const float* __restrict__ seps, const float* __restrict__ deform,
    const float* __restrict__ probs,
    const float* __restrict__ etas, const float* __restrict__ omegas,
    float* __restrict__ part, unsigned int* __restrict__ flags,
    float* __restrict__ out)
{
    __shared__ float4 pts[S * M];   // 25.6 KB  (prim path reuses [0..49])
    __shared__ float trig[S * 8];   // 3.2 KB: per-s {log2|c|,sgn} x {ce,se,cw,sw}
    __shared__ float sbuf[20];      // prim path: sarea[0..15], wsum[16..19]

    int t = threadIdx.x;

    if (blockIdx.x < MAIN_BLOCKS) {
        // ---------- pcl_to_prim ----------
        int b  = blockIdx.x >> 5;        // 32 n-chunks per batch
        int n0 = (blockIdx.x & 31) * 64;

        // stage 1: per-s trig+log table (sincos/log depend only on s, not m)
        if (t < S) {
            float se_, ce_, sw_, cw_;
            __sincosf(etas[t], &se_, &ce_);
            __sincosf(omegas[t], &sw_, &cw_);
            trig[t * 8 + 0] = hw_log2(fabsf(ce_) + EPSF);
            trig[t * 8 + 1] = sgn_d(ce_);
            trig[t * 8 + 2] = hw_log2(fabsf(se_) + EPSF);
            trig[t * 8 + 3] = sgn_d(se_);
            trig[t * 8 + 4] = hw_log2(fabsf(cw_) + EPSF);
            trig[t * 8 + 5] = sgn_d(cw_);
            trig[t * 8 + 6] = hw_log2(fabsf(sw_) + EPSF);
            trig[t * 8 + 7] = sgn_d(sw_);
        }
        __syncthreads();

        // stage 2: 1600 surface points, 4 exp2 each
        for (int i = t; i < S * M; i += 256) {
            int s = i >> 4, mm = i & 15;
            int bmi = b * M + mm;
            float e1 = seps[bmi * 2 + 0], e2 = seps[bmi * 2 + 1];
            float a1 = sizep[bmi * 3 + 0], a2 = sizep[bmi * 3 + 1], a3 = sizep[bmi * 3 + 2];
            float d0 = deform[bmi * 2 + 0], d1 = deform[bmi * 2 + 1];
            float ce = trig[s * 8 + 1] * hw_exp2(e1 * trig[s * 8 + 0]);
            float se = trig[s * 8 + 3] * hw_exp2(e1 * trig[s * 8 + 2]);
            float cw = trig[s * 8 + 5] * hw_exp2(e2 * trig[s * 8 + 4]);
            float sw = trig[s * 8 + 7] * hw_exp2(e2 * trig[s * 8 + 6]);
            float x = a1 * ce * cw;
            float y = a2 * ce * sw;
            float z = a3 * se;
            float fx = fmaf(d0, se, 1.0f);   // z/a3 == se
            float fy = fmaf(d1, se, 1.0f);
            float4 P;
            P.x = fx * x; P.y = fy * y; P.z = z;
            P.w = P.x * P.x + P.y * P.y + P.z * P.z;
            pts[i] = P;
        }
        __syncthreads();

        int m  = t & 15;
        int nl = t >> 4;
        int bm = b * M + m;
        float R[9];
        quat_R(rot, bm, R);
        float tx = trans[bm * 3 + 0], ty = trans[bm * 3 + 1], tz = trans[bm * 3 + 2];

        // rotated points; j packed in pairs for v_pk_fma_f32
        v2f mx2[2], my2[2], mz2[2], dmin2[2];
        float psq[4];
#pragma unroll
        for (int j = 0; j < 4; j++) {
            int n = n0 + nl + 16 * j;
            float px = pcl[(b * N + n) * 3 + 0];
            float py = pcl[(b * N + n) * 3 + 1];
            float pz = pcl[(b * N + n) * 3 + 2];
            float dx = px - tx, dy = py - ty, dz = pz - tz;
            float X = R[0] * dx + R[1] * dy + R[2] * dz;
            float Y = R[3] * dx + R[4] * dy + R[5] * dz;
            float Z = R[6] * dx + R[7] * dy + R[8] * dz;
            mx2[j >> 1][j & 1] = -2.f * X;
            my2[j >> 1][j & 1] = -2.f * Y;
            mz2[j >> 1][j & 1] = -2.f * Z;
            psq[j] = X * X + Y * Y + Z * Z;
            dmin2[j >> 1][j & 1] = 3.4e38f;
        }

        // min over s of (|P|^2 - 2 P.pt); ping-pong buffers, manual 2x unroll
        auto compute4 = [&](const float4* P4) {
#pragma unroll
            for (int u = 0; u < 4; u++) {
                float4 P = P4[u];
                v2f vx = {P.x, P.x}, vy = {P.y, P.y}, vz = {P.z, P.z}, vw = {P.w, P.w};
#pragma unroll
                for (int p = 0; p < 2; p++) {
                    v2f d = __builtin_elementwise_fma(vx, mx2[p], vw);
                    d = __builtin_elementwise_fma(vy, my2[p], d);
                    d = __builtin_elementwise_fma(vz, mz2[p], d);
                    dmin2[p] = __builtin_elementwise_min(dmin2[p], d);
                }
            }
        };

        float4 Pa[4], Pb[4];
#pragma unroll
        for (int u = 0; u < 4; u++) Pa[u] = pts[u * M + m];
        for (int g = 0; g < 24; g += 2) {           // groups of 4 s; 25 groups total
#pragma unroll
            for (int u = 0; u < 4; u++) Pb[u] = pts[(4 * (g + 1) + u) * M + m];
            compute4(Pa);
#pragma unroll
            for (int u = 0; u < 4; u++) Pa[u] = pts[(4 * (g + 2) + u) * M + m];
            compute4(Pb);
        }
        compute4(Pa);                               // group 24 (s=96..99)

        // ---- in-wave cumprod-sorted sum ----
        float ompr[16];
#pragma unroll
        for (int k = 0; k < 16; k++) ompr[k] = 1.f - probs[b * M + k];
        float pv  = probs[bm];
        float acc = 0.f;
#pragma unroll
        for (int j = 0; j < 4; j++) {
            float key = dmin2[j >> 1][j & 1] + psq[j];
            float prod = 1.f;
#pragma unroll
            for (int k = 0; k < 16; k++) {
                float bk = __shfl(key, k, 16);
                bool before = (bk < key) || (bk == key && k < m);
                prod *= before ? ompr[k] : 1.f;
            }
            acc += key * pv * prod;
        }
        for (int off = 32; off >= 1; off >>= 1) acc += __shfl_down(acc, off);
        if ((t & 63) == 0)
            __hip_atomic_store(&part[blockIdx.x * 4 + (t >> 6)],
                               acc * (1.0f / (B * N)),
                               __ATOMIC_RELAXED, __HIP_MEMORY_SCOPE_AGENT);
        __syncthreads();   // all four partial stores issued before flag
        if (t == 0)
            __hip_atomic_store(&flags[blockIdx.x], 1u,
                               __ATOMIC_RELEASE, __HIP_MEMORY_SCOPE_AGENT);
    } else if (blockIdx.x < TOTAL_BLOCKS) {
        // ---------- prim_to_pcl ----------
        int pb = blockIdx.x - MAIN_BLOCKS;
        int bm = pb >> 1, q = pb & 1;
        int b = bm >> 4, m = bm & 15;
        int s0 = q * 50;

        float4* spts = pts;          // [0..49]
        float* sarea = sbuf;         // [0..15]
        float* wsum  = sbuf + 16;    // [16..19]

        if (t < 50) spts[t] = surf_point(sizep, seps, deform, etas, omegas, bm, s0 + t);
        if (t >= 64 && t < 64 + M) {
            int mm = t - 64;
            float s0s = sizep[(b * M + mm) * 3 + 0];
            float s1s = sizep[(b * M + mm) * 3 + 1];
            float s2s = sizep[(b * M + mm) * 3 + 2];
            float tt = __powf(s0s * s1s, 1.6f) / 3.f + __powf(s0s * s2s, 1.6f) / 3.f
                     + __powf(s1s * s2s, 1.6f) / 3.f;
            sarea[mm] = 4.0f * 3.14159265358979323846f * __powf(tt, 0.625f);
        }
        __syncthreads();

        float R[9];
        quat_R(rot, bm, R);
        float tx = trans[bm * 3 + 0], ty = trans[bm * 3 + 1], tz = trans[bm * 3 + 2];

        int w = t >> 6, lane = t & 63;
        int cnt = (w < 2) ? 13 : 12;
        int off = (w < 2) ? w * 13 : 26 + (w - 2) * 12;

        // Q-transform: d_k(n) = |p-t|^2 - 2(R^T P_k).p + (|P_k|^2 + 2(R^T P_k).t)
        // The 18-op rotation LEAVES the n-loop entirely; per-iter cost ~38 vs ~61.
        // Per-slot precompute: mQ = -2 R^T P (packed pairs); wk deferred to the end.
        v2f mQx2[7], mQy2[7], mQz2[7], mins2[7];
        float wk[14];
#pragma unroll
        for (int k = 0; k < 14; k++) {
            int sl = (k < cnt) ? (off + k) : off;   // pads masked later
            float4 P = spts[sl];
            float Qx = R[0] * P.x + R[3] * P.y + R[6] * P.z;
            float Qy = R[1] * P.x + R[4] * P.y + R[7] * P.z;
            float Qz = R[2] * P.x + R[5] * P.y + R[8] * P.z;
            mQx2[k >> 1][k & 1] = -2.f * Qx;
            mQy2[k >> 1][k & 1] = -2.f * Qy;
            mQz2[k >> 1][k & 1] = -2.f * Qz;
            wk[k] = P.w + 2.f * (Qx * tx + Qy * ty + Qz * tz);
            mins2[k >> 1][k & 1] = 3.4e38f;
        }

        // min over n; 1-deep global prefetch hides L2 latency; packed fma body
        const float* pcb = pcl + b * N * 3;
        float cx = pcb[lane * 3 + 0], cy = pcb[lane * 3 + 1], cz = pcb[lane * 3 + 2];
        for (int i = 0; i < 32; i++) {
            int n2 = (i < 31) ? ((i + 1) * 64 + lane) : lane;
            float nx = pcb[n2 * 3 + 0], ny = pcb[n2 * 3 + 1], nz = pcb[n2 * 3 + 2];
            float dx = cx - tx, dy = cy - ty, dz = cz - tz;
            float dsq = dx * dx + dy * dy + dz * dz;
            v2f vpx = {cx, cx}, vpy = {cy, cy}, vpz = {cz, cz}, vdq = {dsq, dsq};
#pragma unroll
            for (int k = 0; k < 7; k++) {
                v2f d = __builtin_elementwise_fma(mQx2[k], vpx, vdq);
                d = __builtin_elementwise_fma(mQy2[k], vpy, d);
                d = __builtin_elementwise_fma(mQz2[k], vpz, d);
                mins2[k] = __builtin_elementwise_min(mins2[k], d);
            }
            cx = nx; cy = ny; cz = nz;
        }

        float sum = 0.f;
#pragma unroll
        for (int k = 0; k < 14; k++) {
            float v = mins2[k >> 1][k & 1];
            for (int o = 32; o >= 1; o >>= 1) v = fminf(v, __shfl_down(v, o));
            v += wk[k];                            // deferred |P_k|^2 + 2Q_k.t
            sum += (k < cnt) ? v : 0.f;
        }

        if (lane == 0) wsum[w] = sum;
        __syncthreads();
        if (t == 0) {
            float total = wsum[0] + wsum[1] + wsum[2] + wsum[3];
            float asum = 0.f;
            for (int mm = 0; mm < M; mm++) asum += sarea[mm];
            float area = (float)M * sarea[m] / asum;
            __hip_atomic_store(&part[MAIN_BLOCKS * 4 + pb],
                               total * area * (1.0f / (S * B * M)),
                               __ATOMIC_RELAXED, __HIP_MEMORY_SCOPE_AGENT);
            __hip_atomic_store(&flags[blockIdx.x], 1u,
                               __ATOMIC_RELEASE, __HIP_MEMORY_SCOPE_AGENT);
        }
    } else {
        // ---------- reducer: waits on workers (never the other way) ----------
        if (t >= 64) return;
        for (int i = t; i < TOTAL_BLOCKS; i += 64) {
            while (__hip_atomic_load(&flags[i], __ATOMIC_ACQUIRE,
                                     __HIP_MEMORY_SCOPE_AGENT) != 1u)
                __builtin_amdgcn_s_sleep(2);
        }
        __threadfence();
        float ssum = 0.f;
        for (int i = t; i < NPART; i += 64)
            ssum += __hip_atomic_load(&part[i], __ATOMIC_RELAXED,
                                      __HIP_MEMORY_SCOPE_AGENT);
        for (int off = 32; off >= 1; off >>= 1) ssum += __shfl_down(ssum, off);
        if (t == 0) out[0] = ssum;
        // self-reset so next replay is correct even if ws poisoning is skipped
        for (int i = t; i < TOTAL_BLOCKS; i += 64)
            __hip_atomic_store(&flags[i], 0u, __ATOMIC_RELAXED,
                               __HIP_MEMORY_SCOPE_AGENT);
    }
}

extern "C" void kernel_launch(void* const* d_in, const int* in_sizes, int n_in,
                              void* d_out, int out_size, void* d_ws, size_t ws_size,
                              hipStream_t stream)
{
    const float* pcl    = (const float*)d_in[0];
    const float* trans  = (const float*)d_in[1];
    const float* rot    = (const float*)d_in[2];
    const float* sizep  = (const float*)d_in[3];
    const float* seps   = (const float*)d_in[4];
    const float* deform = (const float*)d_in[5];
    const float* probs  = (const float*)d_in[6];
    const float* etas   = (const float*)d_in[7];
    const float* omegas = (const float*)d_in[8];
    float* out = (float*)d_out;
    float* partials = (float*)d_ws;                       // [0, 5120) bytes
    unsigned int* flags = (unsigned int*)((char*)d_ws + 8192);  // [8192, 10240)

    k_all<<<TOTAL_BLOCKS + 1, 256, 0, stream>>>(pcl, trans, rot, sizep, seps,
                                                deform, probs, etas, omegas,
                                                partials, flags, out);
}

// Round 9
// 89.186 us; speedup vs baseline: 1.0796x; 1.0299x over previous
//
#include <hip/hip_runtime.h>
#include <math.h>

#define EPSF 1e-6f

constexpr int B = 8, N = 2048, M = 16, S = 100;
constexpr int MAIN_BLOCKS = B * (N / 64);         // 256: pcl_to_prim, 64 points each
constexpr int PRIM_BLOCKS = B * M * 2;            // 256: prim_to_pcl, (b,m) x half-of-S
constexpr int TOTAL_BLOCKS = MAIN_BLOCKS + PRIM_BLOCKS;  // 512 worker blocks
constexpr int NPART = MAIN_BLOCKS * 4 + PRIM_BLOCKS;     // 1280 partials in d_ws

typedef float v2f __attribute__((ext_vector_type(2)));   // -> v_pk_fma_f32 pairs

// fast hw transcendentals (avoid __exp2f/__log2f: glibc math.h macro collision)
__device__ __forceinline__ float hw_exp2(float x) { return __builtin_amdgcn_exp2f(x); }
__device__ __forceinline__ float hw_log2(float x) { return __builtin_amdgcn_logf(x); }

__device__ __forceinline__ float fexp_d(float x, float p) {
    float sg = (x > 0.f) ? 1.f : ((x < 0.f) ? -1.f : 0.f);
    return sg * __powf(fabsf(x) + EPSF, p);
}

__device__ __forceinline__ float sgn_d(float x) {
    return (x > 0.f) ? 1.f : ((x < 0.f) ? -1.f : 0.f);
}

// quaternion (w,x,y,z) at rot[bm*4..] -> row-major 3x3
__device__ __forceinline__ void quat_R(const float* __restrict__ rot, int bm, float R[9]) {
    float w = rot[bm * 4 + 0], x = rot[bm * 4 + 1], y = rot[bm * 4 + 2], z = rot[bm * 4 + 3];
    float inv = 1.0f / (sqrtf(w * w + x * x + y * y + z * z) + EPSF);
    w *= inv; x *= inv; y *= inv; z *= inv;
    R[0] = 1.f - 2.f * (y * y + z * z); R[1] = 2.f * (x * y - w * z); R[2] = 2.f * (x * z + w * y);
    R[3] = 2.f * (x * y + w * z); R[4] = 1.f - 2.f * (x * x + z * z); R[5] = 2.f * (y * z - w * x);
    R[6] = 2.f * (x * z - w * y); R[7] = 2.f * (y * z + w * x); R[8] = 1.f - 2.f * (x * x + y * y);
}

// surface point (prim path; 50 pts/block, transcendental cost irrelevant there)
__device__ __forceinline__ float4 surf_point(
    const float* __restrict__ sizep, const float* __restrict__ seps,
    const float* __restrict__ deform, const float* __restrict__ etas,
    const float* __restrict__ omegas, int bm, int s)
{
    float e1 = seps[bm * 2 + 0], e2 = seps[bm * 2 + 1];
    float a1 = sizep[bm * 3 + 0], a2 = sizep[bm * 3 + 1], a3 = sizep[bm * 3 + 2];
    float d0 = deform[bm * 2 + 0], d1 = deform[bm * 2 + 1];
    float se_, ce_, sw_, cw_;
    __sincosf(etas[s], &se_, &ce_);
    __sincosf(omegas[s], &sw_, &cw_);
    float ce = fexp_d(ce_, e1);
    float se = fexp_d(se_, e1);
    float cw = fexp_d(cw_, e2);
    float sw = fexp_d(sw_, e2);
    float x = a1 * ce * cw;
    float y = a2 * ce * sw;
    float z = a3 * se;
    float fx = d0 * (z / a3) + 1.0f;
    float fy = d1 * (z / a3) + 1.0f;
    float4 P;
    P.x = fx * x; P.y = fy * y; P.z = z;
    P.w = P.x * P.x + P.y * P.y + P.z * P.z;
    return P;
}

// ---------------- single fused kernel, 513 blocks ----------------
// [0,256): pcl_to_prim; [256,512): prim_to_pcl; block 512: flag-gated reducer.
// Round-6 lesson: don't grow the grid (per-CU time = sum of resident waves'
// work). Round-8 lesson: don't strip compute out of the latency-bound prim
// n-loop (Q-transform regressed); instead COVER the latency (this round:
// 4-deep register prefetch). Main path identical to the 90.26us round-5 best.
__global__ __launch_bounds__(256) void k_all(
    const float* __restrict__ pcl, const float* __restrict__ trans,
    const float* __restrict__ rot, const float* __restrict__ sizep,
    const float* __restrict__ seps, const float* __restrict__ deform,
    const float* __restrict__ probs,
    const float* __restrict__ etas, const float* __restrict__ omegas,
    float* __restrict__ part, unsigned int* __restrict__ flags,
    float* __restrict__ out)
{
    __shared__ float4 pts[S * M];   // 25.6 KB  (prim path reuses [0..49])
    __shared__ float trig[S * 8];   // 3.2 KB: per-s {log2|c|,sgn} x {ce,se,cw,sw}
    __shared__ float sbuf[20];      // prim path: sarea[0..15], wsum[16..19]

    int t = threadIdx.x;

    if (blockIdx.x < MAIN_BLOCKS) {
        // ---------- pcl_to_prim ----------
        int b  = blockIdx.x >> 5;        // 32 n-chunks per batch
        int n0 = (blockIdx.x & 31) * 64;

        // stage 1: per-s trig+log table (sincos/log depend only on s, not m)
        if (t < S) {
            float se_, ce_, sw_, cw_;
            __sincosf(etas[t], &se_, &ce_);
            __sincosf(omegas[t], &sw_, &cw_);
            trig[t * 8 + 0] = hw_log2(fabsf(ce_) + EPSF);
            trig[t * 8 + 1] = sgn_d(ce_);
            trig[t * 8 + 2] = hw_log2(fabsf(se_) + EPSF);
            trig[t * 8 + 3] = sgn_d(se_);
            trig[t * 8 + 4] = hw_log2(fabsf(cw_) + EPSF);
            trig[t * 8 + 5] = sgn_d(cw_);
            trig[t * 8 + 6] = hw_log2(fabsf(sw_) + EPSF);
            trig[t * 8 + 7] = sgn_d(sw_);
        }
        __syncthreads();

        // stage 2: 1600 surface points, 4 exp2 each
        for (int i = t; i < S * M; i += 256) {
            int s = i >> 4, mm = i & 15;
            int bmi = b * M + mm;
            float e1 = seps[bmi * 2 + 0], e2 = seps[bmi * 2 + 1];
            float a1 = sizep[bmi * 3 + 0], a2 = sizep[bmi * 3 + 1], a3 = sizep[bmi * 3 + 2];
            float d0 = deform[bmi * 2 + 0], d1 = deform[bmi * 2 + 1];
            float ce = trig[s * 8 + 1] * hw_exp2(e1 * trig[s * 8 + 0]);
            float se = trig[s * 8 + 3] * hw_exp2(e1 * trig[s * 8 + 2]);
            float cw = trig[s * 8 + 5] * hw_exp2(e2 * trig[s * 8 + 4]);
            float sw = trig[s * 8 + 7] * hw_exp2(e2 * trig[s * 8 + 6]);
            float x = a1 * ce * cw;
            float y = a2 * ce * sw;
            float z = a3 * se;
            float fx = fmaf(d0, se, 1.0f);   // z/a3 == se
            float fy = fmaf(d1, se, 1.0f);
            float4 P;
            P.x = fx * x; P.y = fy * y; P.z = z;
            P.w = P.x * P.x + P.y * P.y + P.z * P.z;
            pts[i] = P;
        }
        __syncthreads();

        int m  = t & 15;
        int nl = t >> 4;
        int bm = b * M + m;
        float R[9];
        quat_R(rot, bm, R);
        float tx = trans[bm * 3 + 0], ty = trans[bm * 3 + 1], tz = trans[bm * 3 + 2];

        // rotated points; j packed in pairs for v_pk_fma_f32
        v2f mx2[2], my2[2], mz2[2], dmin2[2];
        float psq[4];
#pragma unroll
        for (int j = 0; j < 4; j++) {
            int n = n0 + nl + 16 * j;
            float px = pcl[(b * N + n) * 3 + 0];
            float py = pcl[(b * N + n) * 3 + 1];
            float pz = pcl[(b * N + n) * 3 + 2];
            float dx = px - tx, dy = py - ty, dz = pz - tz;
            float X = R[0] * dx + R[1] * dy + R[2] * dz;
            float Y = R[3] * dx + R[4] * dy + R[5] * dz;
            float Z = R[6] * dx + R[7] * dy + R[8] * dz;
            mx2[j >> 1][j & 1] = -2.f * X;
            my2[j >> 1][j & 1] = -2.f * Y;
            mz2[j >> 1][j & 1] = -2.f * Z;
            psq[j] = X * X + Y * Y + Z * Z;
            dmin2[j >> 1][j & 1] = 3.4e38f;
        }

        // min over s of (|P|^2 - 2 P.pt); ping-pong buffers, manual 2x unroll
        auto compute4 = [&](const float4* P4) {
#pragma unroll
            for (int u = 0; u < 4; u++) {
                float4 P = P4[u];
                v2f vx = {P.x, P.x}, vy = {P.y, P.y}, vz = {P.z, P.z}, vw = {P.w, P.w};
#pragma unroll
                for (int p = 0; p < 2; p++) {
                    v2f d = __builtin_elementwise_fma(vx, mx2[p], vw);
                    d = __builtin_elementwise_fma(vy, my2[p], d);
                    d = __builtin_elementwise_fma(vz, mz2[p], d);
                    dmin2[p] = __builtin_elementwise_min(dmin2[p], d);
                }
            }
        };

        float4 Pa[4], Pb[4];
#pragma unroll
        for (int u = 0; u < 4; u++) Pa[u] = pts[u * M + m];
        for (int g = 0; g < 24; g += 2) {           // groups of 4 s; 25 groups total
#pragma unroll
            for (int u = 0; u < 4; u++) Pb[u] = pts[(4 * (g + 1) + u) * M + m];
            compute4(Pa);
#pragma unroll
            for (int u = 0; u < 4; u++) Pa[u] = pts[(4 * (g + 2) + u) * M + m];
            compute4(Pb);
        }
        compute4(Pa);                               // group 24 (s=96..99)

        // ---- in-wave cumprod-sorted sum ----
        float ompr[16];
#pragma unroll
        for (int k = 0; k < 16; k++) ompr[k] = 1.f - probs[b * M + k];
        float pv  = probs[bm];
        float acc = 0.f;
#pragma unroll
        for (int j = 0; j < 4; j++) {
            float key = dmin2[j >> 1][j & 1] + psq[j];
            float prod = 1.f;
#pragma unroll
            for (int k = 0; k < 16; k++) {
                float bk = __shfl(key, k, 16);
                bool before = (bk < key) || (bk == key && k < m);
                prod *= before ? ompr[k] : 1.f;
            }
            acc += key * pv * prod;
        }
        for (int off = 32; off >= 1; off >>= 1) acc += __shfl_down(acc, off);
        if ((t & 63) == 0)
            __hip_atomic_store(&part[blockIdx.x * 4 + (t >> 6)],
                               acc * (1.0f / (B * N)),
                               __ATOMIC_RELAXED, __HIP_MEMORY_SCOPE_AGENT);
        __syncthreads();   // all four partial stores issued before flag
        if (t == 0)
            __hip_atomic_store(&flags[blockIdx.x], 1u,
                               __ATOMIC_RELEASE, __HIP_MEMORY_SCOPE_AGENT);
    } else if (blockIdx.x < TOTAL_BLOCKS) {
        // ---------- prim_to_pcl ----------
        int pb = blockIdx.x - MAIN_BLOCKS;
        int bm = pb >> 1, q = pb & 1;
        int b = bm >> 4, m = bm & 15;
        int s0 = q * 50;

        float4* spts = pts;          // [0..49]
        float* sarea = sbuf;         // [0..15]
        float* wsum  = sbuf + 16;    // [16..19]

        if (t < 50) spts[t] = surf_point(sizep, seps, deform, etas, omegas, bm, s0 + t);
        if (t >= 64 && t < 64 + M) {
            int mm = t - 64;
            float s0s = sizep[(b * M + mm) * 3 + 0];
            float s1s = sizep[(b * M + mm) * 3 + 1];
            float s2s = sizep[(b * M + mm) * 3 + 2];
            float tt = __powf(s0s * s1s, 1.6f) / 3.f + __powf(s0s * s2s, 1.6f) / 3.f
                     + __powf(s1s * s2s, 1.6f) / 3.f;
            sarea[mm] = 4.0f * 3.14159265358979323846f * __powf(tt, 0.625f);
        }
        __syncthreads();

        float R[9];
        quat_R(rot, bm, R);
        float tx = trans[bm * 3 + 0], ty = trans[bm * 3 + 1], tz = trans[bm * 3 + 2];

        int w = t >> 6, lane = t & 63;
        int cnt = (w < 2) ? 13 : 12;
        int off = (w < 2) ? w * 13 : 26 + (w - 2) * 12;

        // 14 slots packed into 7 v2f pairs (pads map to slot 'off', masked later)
        v2f px2[7], py2[7], pz2[7], mins2[7];
#pragma unroll
        for (int k = 0; k < 14; k++) {
            int sl = (k < cnt) ? (off + k) : off;
            float4 P = spts[sl];
            px2[k >> 1][k & 1] = P.x;
            py2[k >> 1][k & 1] = P.y;
            pz2[k >> 1][k & 1] = P.z;
            mins2[k >> 1][k & 1] = 3.4e38f;
        }

        // min over n, 32 iters in 8 groups of 4; 4-iteration-deep register
        // prefetch (two named banks, static indexing only — rule #20): the 12
        // loads of group g+1 are in flight across ~490 cyc of group-g compute,
        // covering L2/HBM latency that the old 1-deep scheme exposed.
        const float* pcb = pcl + b * N * 3 + lane * 3;  // group g, sub u at [g*768 + u*192]

#define LOADG(x0,y0,z0,x1,y1,z1,x2,y2,z2,x3,y3,z3, g)            \
        { const float* p_ = pcb + (g) * 768;                     \
          x0 = p_[0];   y0 = p_[1];   z0 = p_[2];                \
          x1 = p_[192]; y1 = p_[193]; z1 = p_[194];              \
          x2 = p_[384]; y2 = p_[385]; z2 = p_[386];              \
          x3 = p_[576]; y3 = p_[577]; z3 = p_[578]; }

#define COMP1(cx,cy,cz)                                          \
        { float dx = (cx) - tx, dy = (cy) - ty, dz = (cz) - tz;  \
          float X = R[0] * dx + R[1] * dy + R[2] * dz;           \
          float Y = R[3] * dx + R[4] * dy + R[5] * dz;           \
          float Z = R[6] * dx + R[7] * dy + R[8] * dz;           \
          float Xsq = X * X + Y * Y + Z * Z;                     \
          v2f vmX = {-2.f * X, -2.f * X}, vmY = {-2.f * Y, -2.f * Y}; \
          v2f vmZ = {-2.f * Z, -2.f * Z}, vXq = {Xsq, Xsq};      \
          _Pragma("unroll")                                      \
          for (int k = 0; k < 7; k++) {                          \
              v2f d = __builtin_elementwise_fma(px2[k], vmX, vXq); \
              d = __builtin_elementwise_fma(py2[k], vmY, d);     \
              d = __builtin_elementwise_fma(pz2[k], vmZ, d);     \
              mins2[k] = __builtin_elementwise_min(mins2[k], d); \
          } }

#define COMPG(x0,y0,z0,x1,y1,z1,x2,y2,z2,x3,y3,z3)               \
        COMP1(x0,y0,z0) COMP1(x1,y1,z1) COMP1(x2,y2,z2) COMP1(x3,y3,z3)

        float a0x,a0y,a0z,a1x,a1y,a1z,a2x,a2y,a2z,a3x,a3y,a3z;
        float b0x,b0y,b0z,b1x,b1y,b1z,b2x,b2y,b2z,b3x,b3y,b3z;

        LOADG(a0x,a0y,a0z,a1x,a1y,a1z,a2x,a2y,a2z,a3x,a3y,a3z, 0)
        LOADG(b0x,b0y,b0z,b1x,b1y,b1z,b2x,b2y,b2z,b3x,b3y,b3z, 1)
        COMPG(a0x,a0y,a0z,a1x,a1y,a1z,a2x,a2y,a2z,a3x,a3y,a3z)
        LOADG(a0x,a0y,a0z,a1x,a1y,a1z,a2x,a2y,a2z,a3x,a3y,a3z, 2)
        COMPG(b0x,b0y,b0z,b1x,b1y,b1z,b2x,b2y,b2z,b3x,b3y,b3z)
        LOADG(b0x,b0y,b0z,b1x,b1y,b1z,b2x,b2y,b2z,b3x,b3y,b3z, 3)
        COMPG(a0x,a0y,a0z,a1x,a1y,a1z,a2x,a2y,a2z,a3x,a3y,a3z)
        LOADG(a0x,a0y,a0z,a1x,a1y,a1z,a2x,a2y,a2z,a3x,a3y,a3z, 4)
        COMPG(b0x,b0y,b0z,b1x,b1y,b1z,b2x,b2y,b2z,b3x,b3y,b3z)
        LOADG(b0x,b0y,b0z,b1x,b1y,b1z,b2x,b2y,b2z,b3x,b3y,b3z, 5)
        COMPG(a0x,a0y,a0z,a1x,a1y,a1z,a2x,a2y,a2z,a3x,a3y,a3z)
        LOADG(a0x,a0y,a0z,a1x,a1y,a1z,a2x,a2y,a2z,a3x,a3y,a3z, 6)
        COMPG(b0x,b0y,b0z,b1x,b1y,b1z,b2x,b2y,b2z,b3x,b3y,b3z)
        LOADG(b0x,b0y,b0z,b1x,b1y,b1z,b2x,b2y,b2z,b3x,b3y,b3z, 7)
        COMPG(a0x,a0y,a0z,a1x,a1y,a1z,a2x,a2y,a2z,a3x,a3y,a3z)
        COMPG(b0x,b0y,b0z,b1x,b1y,b1z,b2x,b2y,b2z,b3x,b3y,b3z)

#undef LOADG
#undef COMP1
#undef COMPG

        float sum = 0.f;
#pragma unroll
        for (int k = 0; k < 14; k++) {
            float v = mins2[k >> 1][k & 1];
            for (int o = 32; o >= 1; o >>= 1) v = fminf(v, __shfl_down(v, o));
            int sl = (k < cnt) ? (off + k) : off;
            v += spts[sl].w;                       // add back |P_k|^2
            sum += (k < cnt) ? v : 0.f;
        }

        if (lane == 0) wsum[w] = sum;
        __syncthreads();
        if (t == 0) {
            float total = wsum[0] + wsum[1] + wsum[2] + wsum[3];
            float asum = 0.f;
            for (int mm = 0; mm < M; mm++) asum += sarea[mm];
            float area = (float)M * sarea[m] / asum;
            __hip_atomic_store(&part[MAIN_BLOCKS * 4 + pb],
                               total * area * (1.0f / (S * B * M)),
                               __ATOMIC_RELAXED, __HIP_MEMORY_SCOPE_AGENT);
            __hip_atomic_store(&flags[blockIdx.x], 1u,
                               __ATOMIC_RELEASE, __HIP_MEMORY_SCOPE_AGENT);
        }
    } else {
        // ---------- reducer: waits on workers (never the other way) ----------
        if (t >= 64) return;
        for (int i = t; i < TOTAL_BLOCKS; i += 64) {
            while (__hip_atomic_load(&flags[i], __ATOMIC_ACQUIRE,
                                     __HIP_MEMORY_SCOPE_AGENT) != 1u)
                __builtin_amdgcn_s_sleep(2);
        }
        __threadfence();
        float ssum = 0.f;
        for (int i = t; i < NPART; i += 64)
            ssum += __hip_atomic_load(&part[i], __ATOMIC_RELAXED,
                                      __HIP_MEMORY_SCOPE_AGENT);
        for (int off = 32; off >= 1; off >>= 1) ssum += __shfl_down(ssum, off);
        if (t == 0) out[0] = ssum;
        // self-reset so next replay is correct even if ws poisoning is skipped
        for (int i = t; i < TOTAL_BLOCKS; i += 64)
            __hip_atomic_store(&flags[i], 0u, __ATOMIC_RELAXED,
                               __HIP_MEMORY_SCOPE_AGENT);
    }
}

extern "C" void kernel_launch(void* const* d_in, const int* in_sizes, int n_in,
                              void* d_out, int out_size, void* d_ws, size_t ws_size,
                              hipStream_t stream)
{
    const float* pcl    = (const float*)d_in[0];
    const float* trans  = (const float*)d_in[1];
    const float* rot    = (const float*)d_in[2];
    const float* sizep  = (const float*)d_in[3];
    const float* seps   = (const float*)d_in[4];
    const float* deform = (const float*)d_in[5];
    const float* probs  = (const float*)d_in[6];
    const float* etas   = (const float*)d_in[7];
    const float* omegas = (const float*)d_in[8];
    float* out = (float*)d_out;
    float* partials = (float*)d_ws;                       // [0, 5120) bytes
    unsigned int* flags = (unsigned int*)((char*)d_ws + 8192);  // [8192, 10240)

    k_all<<<TOTAL_BLOCKS + 1, 256, 0, stream>>>(pcl, trans, rot, sizep, seps,
                                                deform, probs, etas, omegas,
                                                partials, flags, out);
}

// Round 10
// 88.930 us; speedup vs baseline: 1.0827x; 1.0029x over previous
//
#include <hip/hip_runtime.h>
#include <math.h>

#define EPSF 1e-6f

constexpr int B = 8, N = 2048, M = 16, S = 100;
constexpr int MAIN_BLOCKS = B * (N / 64);         // 256: pcl_to_prim, 64 points each
constexpr int PRIM_BLOCKS = B * M * 2;            // 256: prim_to_pcl, (b,m) x half-of-S
constexpr int TOTAL_BLOCKS = MAIN_BLOCKS + PRIM_BLOCKS;  // 512 worker blocks = 2/CU exact
constexpr int NPART = MAIN_BLOCKS * 4 + PRIM_BLOCKS;     // 1280 partials in d_ws

typedef float v2f __attribute__((ext_vector_type(2)));   // -> v_pk_fma_f32 pairs

// fast hw transcendentals (avoid __exp2f/__log2f: glibc math.h macro collision)
__device__ __forceinline__ float hw_exp2(float x) { return __builtin_amdgcn_exp2f(x); }
__device__ __forceinline__ float hw_log2(float x) { return __builtin_amdgcn_logf(x); }

__device__ __forceinline__ float fexp_d(float x, float p) {
    float sg = (x > 0.f) ? 1.f : ((x < 0.f) ? -1.f : 0.f);
    return sg * __powf(fabsf(x) + EPSF, p);
}

__device__ __forceinline__ float sgn_d(float x) {
    return (x > 0.f) ? 1.f : ((x < 0.f) ? -1.f : 0.f);
}

// quaternion values (w,x,y,z) -> row-major 3x3 (value form so loads can be hoisted)
__device__ __forceinline__ void quat_Rv(float w, float x, float y, float z, float R[9]) {
    float inv = 1.0f / (sqrtf(w * w + x * x + y * y + z * z) + EPSF);
    w *= inv; x *= inv; y *= inv; z *= inv;
    R[0] = 1.f - 2.f * (y * y + z * z); R[1] = 2.f * (x * y - w * z); R[2] = 2.f * (x * z + w * y);
    R[3] = 2.f * (x * y + w * z); R[4] = 1.f - 2.f * (x * x + z * z); R[5] = 2.f * (y * z - w * x);
    R[6] = 2.f * (x * z - w * y); R[7] = 2.f * (y * z + w * x); R[8] = 1.f - 2.f * (x * x + y * y);
}

__device__ __forceinline__ void quat_R(const float* __restrict__ rot, int bm, float R[9]) {
    quat_Rv(rot[bm * 4 + 0], rot[bm * 4 + 1], rot[bm * 4 + 2], rot[bm * 4 + 3], R);
}

// surface point (prim path; 50 pts/block, transcendental cost irrelevant there)
__device__ __forceinline__ float4 surf_point(
    const float* __restrict__ sizep, const float* __restrict__ seps,
    const float* __restrict__ deform, const float* __restrict__ etas,
    const float* __restrict__ omegas, int bm, int s)
{
    float e1 = seps[bm * 2 + 0], e2 = seps[bm * 2 + 1];
    float a1 = sizep[bm * 3 + 0], a2 = sizep[bm * 3 + 1], a3 = sizep[bm * 3 + 2];
    float d0 = deform[bm * 2 + 0], d1 = deform[bm * 2 + 1];
    float se_, ce_, sw_, cw_;
    __sincosf(etas[s], &se_, &ce_);
    __sincosf(omegas[s], &sw_, &cw_);
    float ce = fexp_d(ce_, e1);
    float se = fexp_d(se_, e1);
    float cw = fexp_d(cw_, e2);
    float sw = fexp_d(sw_, e2);
    float x = a1 * ce * cw;
    float y = a2 * ce * sw;
    float z = a3 * se;
    float fx = d0 * (z / a3) + 1.0f;
    float fy = d1 * (z / a3) + 1.0f;
    float4 P;
    P.x = fx * x; P.y = fy * y; P.z = z;
    P.w = P.x * P.x + P.y * P.y + P.z * P.z;
    return P;
}

// ---------------- single fused kernel, 512 blocks = 2/CU ----------------
// [0,256): pcl_to_prim; [256,512): prim_to_pcl; reducer folded into block 511
// (R9 had a 513th reducer block -> one CU hosted 3 blocks and straggled).
// Lessons encoded: R6 don't grow the grid; R8 don't strip compute from
// latency-bound loops; R9 DO cover latency (register prefetch). This round:
// cover main-path global-load and LDS-read latency too; keep all accumulation
// orders bit-identical.
__global__ __launch_bounds__(256) void k_all(
    const float* __restrict__ pcl, const float* __restrict__ trans,
    const float* __restrict__ rot, const float* __restrict__ sizep,
    const float* __restrict__ seps, const float* __restrict__ deform,
    const float* __restrict__ probs,
    const float* __restrict__ etas, const float* __restrict__ omegas,
    float* __restrict__ part, unsigned int* __restrict__ flags,
    float* __restrict__ out)
{
    __shared__ float4 pts[S * M];            // 25.6 KB  (prim path reuses [0..49])
    __shared__ __align__(16) float trig[S * 8];  // 3.2 KB per-s {log2|c|,sgn}x4
    __shared__ float sbuf[20];               // prim: sarea[0..15], wsum[16..19]

    int t = threadIdx.x;

    if (blockIdx.x < MAIN_BLOCKS) {
        // ---------- pcl_to_prim ----------
        int b  = blockIdx.x >> 5;        // 32 n-chunks per batch
        int n0 = (blockIdx.x & 31) * 64;
        int m  = t & 15;
        int nl = t >> 4;
        int bm = b * M + m;

        // EARLY register loads: in flight under stage-1/2 staging (covers the
        // ~600cyc global-load bubble that used to sit after the 2nd barrier).
        float qw = rot[bm * 4 + 0], qx = rot[bm * 4 + 1];
        float qy = rot[bm * 4 + 2], qz = rot[bm * 4 + 3];
        float tx = trans[bm * 3 + 0], ty = trans[bm * 3 + 1], tz = trans[bm * 3 + 2];
        float plx[4], ply[4], plz[4];
#pragma unroll
        for (int j = 0; j < 4; j++) {
            int n = n0 + nl + 16 * j;
            plx[j] = pcl[(b * N + n) * 3 + 0];
            ply[j] = pcl[(b * N + n) * 3 + 1];
            plz[j] = pcl[(b * N + n) * 3 + 2];
        }
        float pv = probs[bm];

        // stage 1: per-s trig+log table (sincos/log depend only on s, not m)
        float4* trig4 = (float4*)trig;
        if (t < S) {
            float se_, ce_, sw_, cw_;
            __sincosf(etas[t], &se_, &ce_);
            __sincosf(omegas[t], &sw_, &cw_);
            float4 tA, tB;
            tA.x = hw_log2(fabsf(ce_) + EPSF); tA.y = sgn_d(ce_);
            tA.z = hw_log2(fabsf(se_) + EPSF); tA.w = sgn_d(se_);
            tB.x = hw_log2(fabsf(cw_) + EPSF); tB.y = sgn_d(cw_);
            tB.z = hw_log2(fabsf(sw_) + EPSF); tB.w = sgn_d(sw_);
            trig4[t * 2 + 0] = tA;
            trig4[t * 2 + 1] = tB;
        }
        __syncthreads();

        // stage 2: 1600 surface points, 4 exp2 each. m-index (i&15) is
        // loop-invariant -> per-m params hoisted; trig read as 2x float4.
        {
            float e1 = seps[bm * 2 + 0], e2 = seps[bm * 2 + 1];
            float a1 = sizep[bm * 3 + 0], a2 = sizep[bm * 3 + 1], a3 = sizep[bm * 3 + 2];
            float d0 = deform[bm * 2 + 0], d1 = deform[bm * 2 + 1];
            for (int s = nl; s < S; s += 16) {
                float4 tA = trig4[s * 2 + 0];
                float4 tB = trig4[s * 2 + 1];
                float ce = tA.y * hw_exp2(e1 * tA.x);
                float se = tA.w * hw_exp2(e1 * tA.z);
                float cw = tB.y * hw_exp2(e2 * tB.x);
                float sw = tB.w * hw_exp2(e2 * tB.z);
                float x = a1 * ce * cw;
                float y = a2 * ce * sw;
                float z = a3 * se;
                float fx = fmaf(d0, se, 1.0f);   // z/a3 == se
                float fy = fmaf(d1, se, 1.0f);
                float4 P;
                P.x = fx * x; P.y = fy * y; P.z = z;
                P.w = P.x * P.x + P.y * P.y + P.z * P.z;
                pts[s * M + m] = P;
            }
        }
        __syncthreads();

        float R[9];
        quat_Rv(qw, qx, qy, qz, R);

        // rotated points; j packed in pairs for v_pk_fma_f32
        v2f mx2[2], my2[2], mz2[2], dmin2[2];
        float psq[4];
#pragma unroll
        for (int j = 0; j < 4; j++) {
            float dx = plx[j] - tx, dy = ply[j] - ty, dz = plz[j] - tz;
            float X = R[0] * dx + R[1] * dy + R[2] * dz;
            float Y = R[3] * dx + R[4] * dy + R[5] * dz;
            float Z = R[6] * dx + R[7] * dy + R[8] * dz;
            mx2[j >> 1][j & 1] = -2.f * X;
            my2[j >> 1][j & 1] = -2.f * Y;
            mz2[j >> 1][j & 1] = -2.f * Z;
            psq[j] = X * X + Y * Y + Z * Z;
            dmin2[j >> 1][j & 1] = 3.4e38f;
        }

        // min over s of (|P|^2 - 2 P.pt); 8-wide two-bank ping-pong:
        // 8 ds_read_b128 in flight under 128cyc of compute fully covers the
        // ~120cyc LDS latency (4-wide left ~20cyc/group exposed). s ascending
        // everywhere -> bit-identical accumulation order.
        auto compute4 = [&](const float4* P4) {
#pragma unroll
            for (int u = 0; u < 4; u++) {
                float4 P = P4[u];
                v2f vx = {P.x, P.x}, vy = {P.y, P.y}, vz = {P.z, P.z}, vw = {P.w, P.w};
#pragma unroll
                for (int p = 0; p < 2; p++) {
                    v2f d = __builtin_elementwise_fma(vx, mx2[p], vw);
                    d = __builtin_elementwise_fma(vy, my2[p], d);
                    d = __builtin_elementwise_fma(vz, mz2[p], d);
                    dmin2[p] = __builtin_elementwise_min(dmin2[p], d);
                }
            }
        };
        auto load8 = [&](float4* dst, int sbase) {
#pragma unroll
            for (int u = 0; u < 8; u++) dst[u] = pts[(sbase + u) * M + m];
        };

        float4 Abank[8], Bbank[8];
        load8(Abank, 0);
        for (int gp = 0; gp < 6; gp++) {            // 12 groups of 8 = s 0..95
            load8(Bbank, (2 * gp + 1) * 8);
            compute4(Abank); compute4(Abank + 4);
            if (gp < 5) load8(Abank, (2 * gp + 2) * 8);
            else {
#pragma unroll
                for (int u = 0; u < 4; u++) Abank[u] = pts[(96 + u) * M + m];
            }
            compute4(Bbank); compute4(Bbank + 4);
        }
        compute4(Abank);                            // s = 96..99

        // ---- in-wave cumprod-sorted sum (order identical to prior rounds) ----
        float ompr[16];
#pragma unroll
        for (int k = 0; k < 16; k++) ompr[k] = 1.f - probs[b * M + k];
        float acc = 0.f;
#pragma unroll
        for (int j = 0; j < 4; j++) {
            float key = dmin2[j >> 1][j & 1] + psq[j];
            float prod = 1.f;
#pragma unroll
            for (int k = 0; k < 16; k++) {
                float bk = __shfl(key, k, 16);
                bool before = (bk < key) || (bk == key && k < m);
                prod *= before ? ompr[k] : 1.f;
            }
            acc += key * pv * prod;
        }
        for (int off = 32; off >= 1; off >>= 1) acc += __shfl_down(acc, off);
        if ((t & 63) == 0)
            __hip_atomic_store(&part[blockIdx.x * 4 + (t >> 6)],
                               acc * (1.0f / (B * N)),
                               __ATOMIC_RELAXED, __HIP_MEMORY_SCOPE_AGENT);
        __syncthreads();   // all four partial stores issued before flag
        if (t == 0)
            __hip_atomic_store(&flags[blockIdx.x], 1u,
                               __ATOMIC_RELEASE, __HIP_MEMORY_SCOPE_AGENT);
    } else {
        // ---------- prim_to_pcl (identical to round-9 best) ----------
        int pb = blockIdx.x - MAIN_BLOCKS;
        int bm = pb >> 1, q = pb & 1;
        int b = bm >> 4, m = bm & 15;
        int s0 = q * 50;

        float4* spts = pts;          // [0..49]
        float* sarea = sbuf;         // [0..15]
        float* wsum  = sbuf + 16;    // [16..19]

        if (t < 50) spts[t] = surf_point(sizep, seps, deform, etas, omegas, bm, s0 + t);
        if (t >= 64 && t < 64 + M) {
            int mm = t - 64;
            float s0s = sizep[(b * M + mm) * 3 + 0];
            float s1s = sizep[(b * M + mm) * 3 + 1];
            float s2s = sizep[(b * M + mm) * 3 + 2];
            float tt = __powf(s0s * s1s, 1.6f) / 3.f + __powf(s0s * s2s, 1.6f) / 3.f
                     + __powf(s1s * s2s, 1.6f) / 3.f;
            sarea[mm] = 4.0f * 3.14159265358979323846f * __powf(tt, 0.625f);
        }
        __syncthreads();

        float R[9];
        quat_R(rot, bm, R);
        float tx = trans[bm * 3 + 0], ty = trans[bm * 3 + 1], tz = trans[bm * 3 + 2];

        int w = t >> 6, lane = t & 63;
        int cnt = (w < 2) ? 13 : 12;
        int off = (w < 2) ? w * 13 : 26 + (w - 2) * 12;

        // 14 slots packed into 7 v2f pairs (pads map to slot 'off', masked later)
        v2f px2[7], py2[7], pz2[7], mins2[7];
#pragma unroll
        for (int k = 0; k < 14; k++) {
            int sl = (k < cnt) ? (off + k) : off;
            float4 P = spts[sl];
            px2[k >> 1][k & 1] = P.x;
            py2[k >> 1][k & 1] = P.y;
            pz2[k >> 1][k & 1] = P.z;
            mins2[k >> 1][k & 1] = 3.4e38f;
        }

        // min over n, 32 iters in 8 groups of 4; 4-iteration-deep register
        // prefetch (two named banks, static indexing only): 12 loads of group
        // g+1 in flight across ~490cyc of group-g compute (round-9 win).
        const float* pcb = pcl + b * N * 3 + lane * 3;

#define LOADG(x0,y0,z0,x1,y1,z1,x2,y2,z2,x3,y3,z3, g)            \
        { const float* p_ = pcb + (g) * 768;                     \
          x0 = p_[0];   y0 = p_[1];   z0 = p_[2];                \
          x1 = p_[192]; y1 = p_[193]; z1 = p_[194];              \
          x2 = p_[384]; y2 = p_[385]; z2 = p_[386];              \
          x3 = p_[576]; y3 = p_[577]; z3 = p_[578]; }

#define COMP1(cx,cy,cz)                                          \
        { float dx = (cx) - tx, dy = (cy) - ty, dz = (cz) - tz;  \
          float X = R[0] * dx + R[1] * dy + R[2] * dz;           \
          float Y = R[3] * dx + R[4] * dy + R[5] * dz;           \
          float Z = R[6] * dx + R[7] * dy + R[8] * dz;           \
          float Xsq = X * X + Y * Y + Z * Z;                     \
          v2f vmX = {-2.f * X, -2.f * X}, vmY = {-2.f * Y, -2.f * Y}; \
          v2f vmZ = {-2.f * Z, -2.f * Z}, vXq = {Xsq, Xsq};      \
          _Pragma("unroll")                                      \
          for (int k = 0; k < 7; k++) {                          \
              v2f d = __builtin_elementwise_fma(px2[k], vmX, vXq); \
              d = __builtin_elementwise_fma(py2[k], vmY, d);     \
              d = __builtin_elementwise_fma(pz2[k], vmZ, d);     \
              mins2[k] = __builtin_elementwise_min(mins2[k], d); \
          } }

#define COMPG(x0,y0,z0,x1,y1,z1,x2,y2,z2,x3,y3,z3)               \
        COMP1(x0,y0,z0) COMP1(x1,y1,z1) COMP1(x2,y2,z2) COMP1(x3,y3,z3)

        float a0x,a0y,a0z,a1x,a1y,a1z,a2x,a2y,a2z,a3x,a3y,a3z;
        float b0x,b0y,b0z,b1x,b1y,b1z,b2x,b2y,b2z,b3x,b3y,b3z;

        LOADG(a0x,a0y,a0z,a1x,a1y,a1z,a2x,a2y,a2z,a3x,a3y,a3z, 0)
        LOADG(b0x,b0y,b0z,b1x,b1y,b1z,b2x,b2y,b2z,b3x,b3y,b3z, 1)
        COMPG(a0x,a0y,a0z,a1x,a1y,a1z,a2x,a2y,a2z,a3x,a3y,a3z)
        LOADG(a0x,a0y,a0z,a1x,a1y,a1z,a2x,a2y,a2z,a3x,a3y,a3z, 2)
        COMPG(b0x,b0y,b0z,b1x,b1y,b1z,b2x,b2y,b2z,b3x,b3y,b3z)
        LOADG(b0x,b0y,b0z,b1x,b1y,b1z,b2x,b2y,b2z,b3x,b3y,b3z, 3)
        COMPG(a0x,a0y,a0z,a1x,a1y,a1z,a2x,a2y,a2z,a3x,a3y,a3z)
        LOADG(a0x,a0y,a0z,a1x,a1y,a1z,a2x,a2y,a2z,a3x,a3y,a3z, 4)
        COMPG(b0x,b0y,b0z,b1x,b1y,b1z,b2x,b2y,b2z,b3x,b3y,b3z)
        LOADG(b0x,b0y,b0z,b1x,b1y,b1z,b2x,b2y,b2z,b3x,b3y,b3z, 5)
        COMPG(a0x,a0y,a0z,a1x,a1y,a1z,a2x,a2y,a2z,a3x,a3y,a3z)
        LOADG(a0x,a0y,a0z,a1x,a1y,a1z,a2x,a2y,a2z,a3x,a3y,a3z, 6)
        COMPG(b0x,b0y,b0z,b1x,b1y,b1z,b2x,b2y,b2z,b3x,b3y,b3z)
        LOADG(b0x,b0y,b0z,b1x,b1y,b1z,b2x,b2y,b2z,b3x,b3y,b3z, 7)
        COMPG(a0x,a0y,a0z,a1x,a1y,a1z,a2x,a2y,a2z,a3x,a3y,a3z)
        COMPG(b0x,b0y,b0z,b1x,b1y,b1z,b2x,b2y,b2z,b3x,b3y,b3z)

#undef LOADG
#undef COMP1
#undef COMPG

        float sum = 0.f;
#pragma unroll
        for (int k = 0; k < 14; k++) {
            float v = mins2[k >> 1][k & 1];
            for (int o = 32; o >= 1; o >>= 1) v = fminf(v, __shfl_down(v, o));
            int sl = (k < cnt) ? (off + k) : off;
            v += spts[sl].w;                       // add back |P_k|^2
            sum += (k < cnt) ? v : 0.f;
        }

        if (lane == 0) wsum[w] = sum;
        __syncthreads();
        if (t == 0) {
            float total = wsum[0] + wsum[1] + wsum[2] + wsum[3];
            float asum = 0.f;
            for (int mm = 0; mm < M; mm++) asum += sarea[mm];
            float area = (float)M * sarea[m] / asum;
            __hip_atomic_store(&part[MAIN_BLOCKS * 4 + pb],
                               total * area * (1.0f / (S * B * M)),
                               __ATOMIC_RELAXED, __HIP_MEMORY_SCOPE_AGENT);
            __hip_atomic_store(&flags[blockIdx.x], 1u,
                               __ATOMIC_RELEASE, __HIP_MEMORY_SCOPE_AGENT);
        }

        // ---------- reducer folded into the LAST prim block ----------
        // All 512 worker blocks are co-resident (2/CU, LDS 29KB -> cap 5/CU),
        // and the reducer only waits on workers (never the reverse) -> safe.
        if (blockIdx.x == TOTAL_BLOCKS - 1 && t < 64) {
            for (int i = t; i < TOTAL_BLOCKS; i += 64) {
                while (__hip_atomic_load(&flags[i], __ATOMIC_ACQUIRE,
                                         __HIP_MEMORY_SCOPE_AGENT) != 1u)
                    __builtin_amdgcn_s_sleep(2);
            }
            __threadfence();
            float ssum = 0.f;
            for (int i = t; i < NPART; i += 64)
                ssum += __hip_atomic_load(&part[i], __ATOMIC_RELAXED,
                                          __HIP_MEMORY_SCOPE_AGENT);
            for (int off = 32; off >= 1; off >>= 1) ssum += __shfl_down(ssum, off);
            if (t == 0) out[0] = ssum;
            // self-reset so replay is correct even if ws poisoning is skipped
            for (int i = t; i < TOTAL_BLOCKS; i += 64)
                __hip_atomic_store(&flags[i], 0u, __ATOMIC_RELAXED,
                                   __HIP_MEMORY_SCOPE_AGENT);
        }
    }
}

extern "C" void kernel_launch(void* const* d_in, const int* in_sizes, int n_in,
                              void* d_out, int out_size, void* d_ws, size_t ws_size,
                              hipStream_t stream)
{
    const float* pcl    = (const float*)d_in[0];
    const float* trans  = (const float*)d_in[1];
    const float* rot    = (const float*)d_in[2];
    const float* sizep  = (const float*)d_in[3];
    const float* seps   = (const float*)d_in[4];
    const float* deform = (const float*)d_in[5];
    const float* probs  = (const float*)d_in[6];
    const float* etas   = (const float*)d_in[7];
    const float* omegas = (const float*)d_in[8];
    float* out = (float*)d_out;
    float* partials = (float*)d_ws;                       // [0, 5120) bytes
    unsigned int* flags = (unsigned int*)((char*)d_ws + 8192);  // [8192, 10240)

    k_all<<<TOTAL_BLOCKS, 256, 0, stream>>>(pcl, trans, rot, sizep, seps,
                                            deform, probs, etas, omegas,
                                            partials, flags, out);
}